// Round 1
// baseline (158.814 us; speedup 1.0000x reference)
//
#include <hip/hip_runtime.h>
#include <math.h>

#define Bb 4
#define Rr 4
#define Nn 256
#define Ee 64
#define LAMDA 0.5f
#define EPSf 1e-6f

// ---------------- K1: Q = n_emb @ Wq.T, K = n_emb @ Wk.T ----------------
__global__ __launch_bounds__(64) void qk_proj(
    const float* __restrict__ n_emb, const float* __restrict__ Wq,
    const float* __restrict__ Wk, float* __restrict__ Qo, float* __restrict__ Ko)
{
    int bn = blockIdx.x;        // b*N + n
    int e  = threadIdx.x;       // 0..63
    __shared__ float nrow[Ee];
    nrow[e] = n_emb[bn * Ee + e];
    __syncthreads();
    const float* wq = Wq + e * Ee;
    const float* wk = Wk + e * Ee;
    float q = 0.f, k = 0.f;
#pragma unroll
    for (int f = 0; f < Ee; ++f) {
        float nv = nrow[f];
        q += nv * wq[f];
        k += nv * wk[f];
    }
    Qo[bn * Ee + e] = q;
    Ko[bn * Ee + e] = k;
}

// ---------------- K2: ori[b,q,k] = dot(Q[b,q], K[b,k]) / 4096 ----------------
__global__ __launch_bounds__(256) void ori_kernel(
    const float* __restrict__ Q, const float* __restrict__ K,
    float* __restrict__ ori)
{
    int b = blockIdx.x / Nn;
    int q = blockIdx.x % Nn;
    int k = threadIdx.x;        // 0..255
    __shared__ float4 qs[Ee / 4];
    if (k < Ee / 4) qs[k] = ((const float4*)(Q + (b * Nn + q) * Ee))[k];
    __syncthreads();
    const float4* kp = (const float4*)(K + (b * Nn + k) * Ee);
    float acc = 0.f;
#pragma unroll
    for (int u = 0; u < Ee / 4; ++u) {
        float4 kv = kp[u];
        float4 qv = qs[u];
        acc += qv.x * kv.x + qv.y * kv.y + qv.z * kv.z + qv.w * kv.w;
    }
    ori[(b * Nn + q) * Nn + k] = acc * (1.0f / 4096.0f);
}

// ---------------- block-wide sum over 256 threads ----------------
__device__ __forceinline__ float block_sum256(float v, float* s_red) {
#pragma unroll
    for (int m = 32; m >= 1; m >>= 1) v += __shfl_xor(v, m);
    int wid  = threadIdx.x >> 6;
    int lane = threadIdx.x & 63;
    if (lane == 0) s_red[wid] = v;
    __syncthreads();
    float tot = s_red[0] + s_red[1] + s_red[2] + s_red[3];
    __syncthreads();
    return tot;
}

// ---------------- K3: the heavy fused kernel ----------------
// One block per (b, r, i) row: 4096 blocks x 256 threads.
__global__ __launch_bounds__(256) void raa_kernel(
    const float* __restrict__ h_adj, const float* __restrict__ r_adj,
    const float* __restrict__ t_adj, const float* __restrict__ mask_r,
    const float* __restrict__ mask_u, const float* __restrict__ ori,
    float* __restrict__ out)
{
    const int blk = blockIdx.x;            // (b*R + r)*N + i
    const int b   = blk / (Rr * Nn);
    const int i   = blk % Nn;

    const int t     = threadIdx.x;
    const int jloc  = t >> 2;              // 0..63
    const int chunk = t & 3;               // 0..3

    const int rowbase = blk * (Nn * Ee);   // < 2^27, fits int

    __shared__ float s_pla[Nn];
    __shared__ float s_red[4];

    // Phase 1: pla_scores[j] = || h + r - t ||_2 over E=64
#pragma unroll
    for (int p = 0; p < 4; ++p) {
        int j   = p * 64 + jloc;
        int off = rowbase + j * Ee + chunk * 16;
        const float4* hp = (const float4*)(h_adj + off);
        const float4* rp = (const float4*)(r_adj + off);
        const float4* tp = (const float4*)(t_adj + off);
        float acc = 0.f;
#pragma unroll
        for (int u = 0; u < 4; ++u) {
            float4 hv = hp[u];
            float4 rv = rp[u];
            float4 tv = tp[u];
            float dx = hv.x + rv.x - tv.x;
            float dy = hv.y + rv.y - tv.y;
            float dz = hv.z + rv.z - tv.z;
            float dw = hv.w + rv.w - tv.w;
            acc += dx * dx + dy * dy + dz * dz + dw * dw;
        }
        acc += __shfl_xor(acc, 1);
        acc += __shfl_xor(acc, 2);
        if (chunk == 0) s_pla[j] = sqrtf(acc);
    }
    __syncthreads();

    // Phase 2: masked softmax-ish chain, thread j owns column j
    const int j     = t;
    const int mbase = blk * Nn;

    float e1 = expf(-s_pla[j]) * mask_r[mbase + j];
    float s1 = block_sum256(e1, s_red);
    float w  = e1 / (s1 + EPSf);

    float o   = ori[(b * Nn + i) * Nn + j];
    float raa = o * (1.0f + LAMDA * w);

    float e2 = expf(raa) * mask_u[mbase + j];
    float s2 = block_sum256(e2, s_red);

    out[mbase + j] = e2 / (s2 + EPSf);
}

extern "C" void kernel_launch(void* const* d_in, const int* in_sizes, int n_in,
                              void* d_out, int out_size, void* d_ws, size_t ws_size,
                              hipStream_t stream) {
    const float* n_emb  = (const float*)d_in[0];
    const float* h_adj  = (const float*)d_in[1];
    const float* r_adj  = (const float*)d_in[2];
    const float* t_adj  = (const float*)d_in[3];
    const float* mask_r = (const float*)d_in[4];
    const float* mask_u = (const float*)d_in[5];
    const float* Wq     = (const float*)d_in[6];
    const float* Wk     = (const float*)d_in[7];
    float* out = (float*)d_out;

    float* ws  = (float*)d_ws;
    float* Qw  = ws;                        // B*N*E = 65536 floats
    float* Kw  = ws + Bb * Nn * Ee;         // 65536 floats
    float* ori = ws + 2 * Bb * Nn * Ee;     // B*N*N = 262144 floats

    qk_proj<<<Bb * Nn, 64, 0, stream>>>(n_emb, Wq, Wk, Qw, Kw);
    ori_kernel<<<Bb * Nn, 256, 0, stream>>>(Qw, Kw, ori);
    raa_kernel<<<Bb * Rr * Nn, 256, 0, stream>>>(h_adj, r_adj, t_adj,
                                                 mask_r, mask_u, ori, out);
}